// Round 2
// baseline (680.303 us; speedup 1.0000x reference)
//
#include <hip/hip_runtime.h>
#include <hip/hip_bf16.h>
#include <stdint.h>

// SparseLinear: out[n][o] = sum_i x[n][i] * (mask[o][i] ? W[o][i] : 0) + bias[o]
// = dense GEMM A(8192x4096) * B^T(4096x4096) + bias, computed in bf16 MFMA.
//
// Mask dtype (uint8 bool vs int32 bool) is detected ON DEVICE each call:
// flag stored in d_out[0] (overwritten later by the GEMM epilogue).
//
// Declared risks: bf16 rounding vs f32 reference (exp. ~0.1% of absmax);
// ws_size >= 96 MB.

#define MDIM 8192
#define NDIM 4096
#define KDIM 4096

typedef __bf16   bf16x8 __attribute__((ext_vector_type(8)));
typedef float    f32x4  __attribute__((ext_vector_type(4)));
typedef uint16_t u16x8  __attribute__((ext_vector_type(8)));

__device__ __forceinline__ uint16_t f32_to_bf16_rne(float f) {
  union { float f; uint32_t u; } v; v.f = f;
  uint32_t u = v.u;
  return (uint16_t)((u + 0x7fffu + ((u >> 16) & 1u)) >> 16);
}

// ---- mask dtype detection ----
// Reads first 4096 u32 words (16 KB — safe: mask buffer >= 16 MB either way).
// int32-bool: every word is 0 or 1. uint8-bool: P(word in {0,1}) ~= 0.73,
// so 4096 words all in {0,1} has probability ~0. flag=1 => uint8, 0 => int32.
__global__ void detect_mask_kernel(const uint32_t* __restrict__ mask,
                                   int* __restrict__ flag) {
  __shared__ int any_nonbool;
  if (threadIdx.x == 0) any_nonbool = 0;
  __syncthreads();
  int bad = 0;
  for (int i = threadIdx.x; i < 4096; i += 256) {
    uint32_t w = mask[i];
    bad |= (w > 1u) ? 1 : 0;
  }
  if (bad) any_nonbool = 1;   // benign race: all writers store 1
  __syncthreads();
  if (threadIdx.x == 0) *flag = any_nonbool;
}

// ---- conversion kernels (memory-bound, vectorized 8 elems/thread) ----

__global__ void cvt_x_kernel(const float* __restrict__ x,
                             uint16_t* __restrict__ xh, int n8) {
  int i = blockIdx.x * blockDim.x + threadIdx.x;
  if (i >= n8) return;
  const float4* src = (const float4*)x + (size_t)i * 2;
  float4 a = src[0], b = src[1];
  u16x8 o;
  o[0] = f32_to_bf16_rne(a.x); o[1] = f32_to_bf16_rne(a.y);
  o[2] = f32_to_bf16_rne(a.z); o[3] = f32_to_bf16_rne(a.w);
  o[4] = f32_to_bf16_rne(b.x); o[5] = f32_to_bf16_rne(b.y);
  o[6] = f32_to_bf16_rne(b.z); o[7] = f32_to_bf16_rne(b.w);
  *((u16x8*)xh + i) = o;
}

__global__ void cvt_w_kernel(const float* __restrict__ w,
                             const void* __restrict__ mask,
                             const int* __restrict__ flag,
                             uint16_t* __restrict__ wh, int n8) {
  int i = blockIdx.x * blockDim.x + threadIdx.x;
  if (i >= n8) return;
  const float4* src = (const float4*)w + (size_t)i * 2;
  float4 a = src[0], b = src[1];
  float vals[8] = {a.x, a.y, a.z, a.w, b.x, b.y, b.z, b.w};
  int m[8];
  if (*flag) {  // uniform branch: uint8 bool
    uint64_t mb = *((const uint64_t*)mask + i);
#pragma unroll
    for (int j = 0; j < 8; ++j) m[j] = (int)((mb >> (8 * j)) & 0xffu);
  } else {      // int32 bool
    const int4* mp = (const int4*)mask + (size_t)i * 2;
    int4 ma = mp[0], mb4 = mp[1];
    m[0] = ma.x; m[1] = ma.y; m[2] = ma.z; m[3] = ma.w;
    m[4] = mb4.x; m[5] = mb4.y; m[6] = mb4.z; m[7] = mb4.w;
  }
  u16x8 o;
#pragma unroll
  for (int j = 0; j < 8; ++j)
    o[j] = m[j] ? f32_to_bf16_rne(vals[j]) : (uint16_t)0;
  *((u16x8*)wh + i) = o;
}

// ---- bf16 MFMA GEMM: C = A * B^T + bias ----
// A: M x K bf16 row-major, B: N x K bf16 row-major (both operands load
// identically: 8 contiguous bf16 along K per lane).
// 128x128 tile, BK=64, 4 waves (2x2), each wave 64x64 = 4x4 16x16 frags.
// LDS: linear dest for global_load_lds; XOR swizzle (row&7)<<4 applied on the
// pre-swizzled GLOBAL source and on ds_read (rule 21: both-sides involution).
// Bank math: ds_read_b128 lanes land on slot (fq ^ (fr&7)) -> 8 lanes per
// 16B-slot x 8 slots = conflict-free minimum (8 phases x 32 banks).

__global__ __launch_bounds__(256) void gemm_bias_kernel(
    const uint16_t* __restrict__ A, const uint16_t* __restrict__ B,
    const float* __restrict__ bias, float* __restrict__ C) {
  constexpr int BM = 128, BN = 128, BK = 64;
  constexpr int NBN = NDIM / BN;          // 32 col-blocks
  constexpr int ROWB = BK * 2;            // 128 bytes per LDS row

  __shared__ __align__(16) uint8_t smem[2 * BM * BK * 2];  // 32 KB
  uint8_t* smA = smem;
  uint8_t* smB = smem + BM * BK * 2;

  // XCD-aware swizzle: grid = 2048, divisible by 8 -> simple form is bijective
  const int bid = blockIdx.x;
  const int cpx = gridDim.x >> 3;
  const int wg  = (bid & 7) * cpx + (bid >> 3);
  const int bm  = wg / NBN;
  const int bn  = wg % NBN;

  const int tid  = threadIdx.x;
  const int wave = tid >> 6;
  const int lane = tid & 63;
  const int wm = wave >> 1, wn = wave & 1;
  const int fr = lane & 15;   // frag row (A) / frag col (B)
  const int fq = lane >> 4;   // k-quarter

  // staging addressing: thread t covers linear LDS bytes is*4096 + t*16
  const int trow = tid >> 3;             // 0..31 (row within a 32-row issue)
  const int tcb  = (tid & 7) << 4;       // byte col 0..112
  const int tcol = (tcb ^ ((trow & 7) << 4)) >> 1;  // pre-swizzled elem col

  const uint16_t* Ablk = A + (size_t)bm * BM * KDIM;
  const uint16_t* Bblk = B + (size_t)bn * BN * KDIM;

  // compute-side addressing
  const int swz = (lane & 7) << 4;       // == (fr&7)<<4, rows differ by mult of 16
  const int rdA = (wm * 64 + fr) * ROWB;
  const int rdB = (wn * 64 + fr) * ROWB;
  const int cb0 = fq * 16;

  f32x4 acc[4][4] = {};

  for (int k0 = 0; k0 < KDIM; k0 += BK) {
#pragma unroll
    for (int is = 0; is < 4; ++is) {
      const uint16_t* src = Ablk + (size_t)(is * 32 + trow) * KDIM + (k0 + tcol);
      __builtin_amdgcn_global_load_lds(
          (const __attribute__((address_space(1))) void*)src,
          (__attribute__((address_space(3))) void*)(smA + is * 4096 + wave * 1024),
          16, 0, 0);
    }
#pragma unroll
    for (int is = 0; is < 4; ++is) {
      const uint16_t* src = Bblk + (size_t)(is * 32 + trow) * KDIM + (k0 + tcol);
      __builtin_amdgcn_global_load_lds(
          (const __attribute__((address_space(1))) void*)src,
          (__attribute__((address_space(3))) void*)(smB + is * 4096 + wave * 1024),
          16, 0, 0);
    }
    __syncthreads();  // compiler drains vmcnt before s_barrier (m97 structure)

#pragma unroll
    for (int ks = 0; ks < 2; ++ks) {
      const int cb = cb0 + ks * 64;
      bf16x8 af[4], bfr[4];
#pragma unroll
      for (int mi = 0; mi < 4; ++mi)
        af[mi] = *(const bf16x8*)(smA + rdA + mi * 16 * ROWB + (cb ^ swz));
#pragma unroll
      for (int ni = 0; ni < 4; ++ni)
        bfr[ni] = *(const bf16x8*)(smB + rdB + ni * 16 * ROWB + (cb ^ swz));
#pragma unroll
      for (int mi = 0; mi < 4; ++mi)
#pragma unroll
        for (int ni = 0; ni < 4; ++ni)
          acc[mi][ni] = __builtin_amdgcn_mfma_f32_16x16x32_bf16(
              af[mi], bfr[ni], acc[mi][ni], 0, 0, 0);
    }
    __syncthreads();
  }

  // epilogue: C/D layout col = lane&15, row = (lane>>4)*4 + reg (m89-verified)
  const int rowg0 = bm * BM + wm * 64 + fq * 4;
  const int colg0 = bn * BN + wn * 64 + fr;
#pragma unroll
  for (int ni = 0; ni < 4; ++ni) {
    const int col = colg0 + ni * 16;
    const float bv = bias[col];
#pragma unroll
    for (int mi = 0; mi < 4; ++mi) {
#pragma unroll
      for (int j = 0; j < 4; ++j) {
        const int row = rowg0 + mi * 16 + j;
        C[(size_t)row * NDIM + col] = acc[mi][ni][j] + bv;
      }
    }
  }
}

extern "C" void kernel_launch(void* const* d_in, const int* in_sizes, int n_in,
                              void* d_out, int out_size, void* d_ws, size_t ws_size,
                              hipStream_t stream) {
  const float* x    = (const float*)d_in[0];
  const float* w    = (const float*)d_in[1];
  const void*  mk   = (const void*)d_in[2];
  const float* bias = (const float*)d_in[3];
  float* out        = (float*)d_out;

  const size_t need = (size_t)MDIM * KDIM * 2 + (size_t)NDIM * KDIM * 2;
  if (ws_size < need) return;  // guard: fail loud (poisoned out), don't corrupt

  uint16_t* xh = (uint16_t*)d_ws;
  uint16_t* wh = xh + (size_t)MDIM * KDIM;

  // flag lives in d_out[0]; fully overwritten by the GEMM epilogue afterwards
  int* flag = (int*)d_out;
  detect_mask_kernel<<<1, 256, 0, stream>>>((const uint32_t*)mk, flag);

  const int nx8 = MDIM * KDIM / 8;  // 4,194,304
  const int nw8 = NDIM * KDIM / 8;  // 2,097,152
  cvt_x_kernel<<<nx8 / 256, 256, 0, stream>>>(x, xh, nx8);
  cvt_w_kernel<<<nw8 / 256, 256, 0, stream>>>(w, mk, flag, wh, nw8);

  const int grid = (MDIM / 128) * (NDIM / 128);  // 2048
  gemm_bias_kernel<<<grid, 256, 0, stream>>>(xh, wh, bias, out);
}

// Round 4
// 591.245 us; speedup vs baseline: 1.1506x; 1.1506x over previous
//
#include <hip/hip_runtime.h>
#include <hip/hip_bf16.h>
#include <stdint.h>

// SparseLinear: out = x @ (W*mask)^T + b  ==  bf16 MFMA GEMM, M=8192 N=4096 K=4096.
// R4 (= R3 re-audit + grid-stride cvt): 256x256 tile, BK=64, 8 waves,
// double-buffered LDS (128 KiB), counted vmcnt(8) pipeline (T3+T4), setprio (T5),
// XCD swizzle (T1), XOR bank swizzle (T2).
// Ledger: STAGE(t+2 -> buf[t&1]) issued only after the barrier ending tile t's
// reads; COMPUTE(t+1) only after vmcnt(8)+barrier guarantees its 8 loads landed.
// All ds_reads are consumed by MFMAs before each barrier (no in-flight reads
// cross a barrier).

#define MDIM 8192
#define NDIM 4096
#define KDIM 4096

typedef __bf16   bf16x8 __attribute__((ext_vector_type(8)));
typedef float    f32x4  __attribute__((ext_vector_type(4)));
typedef uint16_t u16x8  __attribute__((ext_vector_type(8)));

__device__ __forceinline__ uint16_t f32_to_bf16_rne(float f) {
  union { float f; uint32_t u; } v; v.f = f;
  uint32_t u = v.u;
  return (uint16_t)((u + 0x7fffu + ((u >> 16) & 1u)) >> 16);
}

// ---- mask dtype detection (uint8 bool vs int32 bool), flag -> d_out[0] ----
__global__ void detect_mask_kernel(const uint32_t* __restrict__ mask,
                                   int* __restrict__ flag) {
  __shared__ int any_nonbool;
  if (threadIdx.x == 0) any_nonbool = 0;
  __syncthreads();
  int bad = 0;
  for (int i = threadIdx.x; i < 4096; i += 256) {
    uint32_t w = mask[i];
    bad |= (w > 1u) ? 1 : 0;
  }
  if (bad) any_nonbool = 1;
  __syncthreads();
  if (threadIdx.x == 0) *flag = any_nonbool;
}

// ---- conversion kernels (grid-stride, capped grid per G11) ----
__global__ void cvt_x_kernel(const float* __restrict__ x,
                             uint16_t* __restrict__ xh, int n8) {
  const int stride = gridDim.x * blockDim.x;
  for (int i = blockIdx.x * blockDim.x + threadIdx.x; i < n8; i += stride) {
    const float4* src = (const float4*)x + (size_t)i * 2;
    float4 a = src[0], b = src[1];
    u16x8 o;
    o[0] = f32_to_bf16_rne(a.x); o[1] = f32_to_bf16_rne(a.y);
    o[2] = f32_to_bf16_rne(a.z); o[3] = f32_to_bf16_rne(a.w);
    o[4] = f32_to_bf16_rne(b.x); o[5] = f32_to_bf16_rne(b.y);
    o[6] = f32_to_bf16_rne(b.z); o[7] = f32_to_bf16_rne(b.w);
    *((u16x8*)xh + i) = o;
  }
}

__global__ void cvt_w_kernel(const float* __restrict__ w,
                             const void* __restrict__ mask,
                             const int* __restrict__ flag,
                             uint16_t* __restrict__ wh, int n8) {
  const int stride = gridDim.x * blockDim.x;
  const int isU8 = *flag;  // wave-uniform
  for (int i = blockIdx.x * blockDim.x + threadIdx.x; i < n8; i += stride) {
    const float4* src = (const float4*)w + (size_t)i * 2;
    float4 a = src[0], b = src[1];
    float vals[8] = {a.x, a.y, a.z, a.w, b.x, b.y, b.z, b.w};
    int m[8];
    if (isU8) {  // uint8 bool
      uint64_t mb = *((const uint64_t*)mask + i);
#pragma unroll
      for (int j = 0; j < 8; ++j) m[j] = (int)((mb >> (8 * j)) & 0xffu);
    } else {     // int32 bool
      const int4* mp = (const int4*)mask + (size_t)i * 2;
      int4 ma = mp[0], mb4 = mp[1];
      m[0] = ma.x; m[1] = ma.y; m[2] = ma.z; m[3] = ma.w;
      m[4] = mb4.x; m[5] = mb4.y; m[6] = mb4.z; m[7] = mb4.w;
    }
    u16x8 o;
#pragma unroll
    for (int j = 0; j < 8; ++j)
      o[j] = m[j] ? f32_to_bf16_rne(vals[j]) : (uint16_t)0;
    *((u16x8*)wh + i) = o;
  }
}

// ---- pipelined 256^2 bf16 MFMA GEMM ----

#define BARRIER() do { asm volatile("" ::: "memory");            \
                       __builtin_amdgcn_s_barrier();             \
                       asm volatile("" ::: "memory"); } while (0)
#define WAITV8()  asm volatile("s_waitcnt vmcnt(8)" ::: "memory")
#define WAITV0()  asm volatile("s_waitcnt vmcnt(0)" ::: "memory")

__global__ __launch_bounds__(512, 2) void gemm_bias_256(
    const uint16_t* __restrict__ A, const uint16_t* __restrict__ B,
    const float* __restrict__ bias, float* __restrict__ C) {
  constexpr int BM = 256, BN = 256, BK = 64;
  constexpr int NT  = KDIM / BK;     // 64 K-tiles
  constexpr int NBN = NDIM / BN;     // 16 col-blocks

  // [2 dbuf][A 32K | B 32K] = 128 KiB
  __shared__ __align__(16) uint8_t smem[2 * 65536];

  const int bid = blockIdx.x;
  const int cpx = gridDim.x >> 3;            // 512/8 = 64, bijective
  const int wg  = (bid & 7) * cpx + (bid >> 3);
  const int bm  = wg / NBN, bn = wg % NBN;

  const int tid  = threadIdx.x;
  const int wave = tid >> 6, lane = tid & 63;
  const int wm = wave >> 2, wn = wave & 3;   // 2x4 wave grid, 128x64 per wave
  const int fr = lane & 15, fq = lane >> 4;

  // staging: 512 thr x 16 B = 8 KB = 64 rows per stage op; 4 ops per operand
  const int trow = tid >> 3;                         // 0..63
  const int tcb  = (tid & 7) << 4;                   // byte col
  const int tcol = (tcb ^ ((trow & 7) << 4)) >> 1;   // pre-swizzled elem col
  const uint16_t* Ab = A + (size_t)bm * BM * KDIM;
  const uint16_t* Bb = B + (size_t)bn * BN * KDIM;
  const size_t aoff = (size_t)trow * KDIM + tcol;

  // read slots: byte col = ((ks*4 + fq) ^ (fr&7)) << 4; cancels the write-side
  // swizzle because row&7 == fr&7 for every read row (offsets are mult. of 8)
  const int c0 = ((fq) ^ (fr & 7)) << 4;
  const int c1 = ((4 + fq) ^ (fr & 7)) << 4;

  f32x4 acc[8][4] = {};

#define STAGE(tile, bufbase) do {                                              \
    const uint16_t* sa = Ab + (size_t)(tile) * BK + aoff;                      \
    const uint16_t* sb = Bb + (size_t)(tile) * BK + aoff;                      \
    _Pragma("unroll")                                                          \
    for (int is = 0; is < 4; ++is) {                                           \
      __builtin_amdgcn_global_load_lds(                                        \
          (const __attribute__((address_space(1))) void*)(sa + (size_t)is * 64 * KDIM), \
          (__attribute__((address_space(3))) void*)(smem + (bufbase) + is * 8192 + wave * 1024), \
          16, 0, 0);                                                           \
      __builtin_amdgcn_global_load_lds(                                        \
          (const __attribute__((address_space(1))) void*)(sb + (size_t)is * 64 * KDIM), \
          (__attribute__((address_space(3))) void*)(smem + (bufbase) + 32768 + is * 8192 + wave * 1024), \
          16, 0, 0);                                                           \
    }                                                                          \
  } while (0)

#define COMPUTE(bufbase) do {                                                  \
    const uint8_t* bA = smem + (bufbase);                                      \
    const uint8_t* bB = smem + (bufbase) + 32768;                              \
    bf16x8 bfrag[4][2];                                                        \
    _Pragma("unroll")                                                          \
    for (int ni = 0; ni < 4; ++ni) {                                           \
      const int brow = wn * 64 + ni * 16 + fr;                                 \
      bfrag[ni][0] = *(const bf16x8*)(bB + brow * 128 + c0);                   \
      bfrag[ni][1] = *(const bf16x8*)(bB + brow * 128 + c1);                   \
    }                                                                          \
    _Pragma("unroll")                                                          \
    for (int mh = 0; mh < 2; ++mh) {                                           \
      bf16x8 afrag[4][2];                                                      \
      _Pragma("unroll")                                                        \
      for (int mi = 0; mi < 4; ++mi) {                                         \
        const int arow = wm * 128 + mh * 64 + mi * 16 + fr;                    \
        afrag[mi][0] = *(const bf16x8*)(bA + arow * 128 + c0);                 \
        afrag[mi][1] = *(const bf16x8*)(bA + arow * 128 + c1);                 \
      }                                                                        \
      __builtin_amdgcn_s_setprio(1);                                          \
      _Pragma("unroll")                                                        \
      for (int mi = 0; mi < 4; ++mi)                                           \
        _Pragma("unroll")                                                      \
        for (int ni = 0; ni < 4; ++ni) {                                       \
          acc[mh * 4 + mi][ni] = __builtin_amdgcn_mfma_f32_16x16x32_bf16(      \
              afrag[mi][0], bfrag[ni][0], acc[mh * 4 + mi][ni], 0, 0, 0);      \
          acc[mh * 4 + mi][ni] = __builtin_amdgcn_mfma_f32_16x16x32_bf16(      \
              afrag[mi][1], bfrag[ni][1], acc[mh * 4 + mi][ni], 0, 0, 0);      \
        }                                                                      \
      __builtin_amdgcn_s_setprio(0);                                          \
    }                                                                          \
  } while (0)

  // prologue: tiles 0 and 1 in flight; wait tile 0 landed (8 newest may fly)
  STAGE(0, 0);
  STAGE(1, 65536);
  WAITV8();
  BARRIER();

  for (int t = 0; t < NT; ++t) {
    const uint32_t bo = (uint32_t)(t & 1) * 65536u;
    COMPUTE(bo);
    BARRIER();                       // all waves done reading buf[t&1]
    if (t + 2 < NT) {
      STAGE(t + 2, bo);              // refill freed buffer
      WAITV8();                      // tile t+1 landed; t+2's 8 stay in flight
      BARRIER();
    } else if (t + 1 < NT) {
      WAITV0();                      // drain for final tile
      BARRIER();
    }
  }

  // epilogue: C/D layout col = lane&15, row = (lane>>4)*4 + reg
  const int rowg0 = bm * BM + wm * 128 + fq * 4;
  const int colg0 = bn * BN + wn * 64 + fr;
#pragma unroll
  for (int ni = 0; ni < 4; ++ni) {
    const int col = colg0 + ni * 16;
    const float bv = bias[col];
#pragma unroll
    for (int mi = 0; mi < 8; ++mi) {
#pragma unroll
      for (int j = 0; j < 4; ++j) {
        const int row = rowg0 + mi * 16 + j;
        C[(size_t)row * NDIM + col] = acc[mi][ni][j] + bv;
      }
    }
  }
#undef STAGE
#undef COMPUTE
}

extern "C" void kernel_launch(void* const* d_in, const int* in_sizes, int n_in,
                              void* d_out, int out_size, void* d_ws, size_t ws_size,
                              hipStream_t stream) {
  const float* x    = (const float*)d_in[0];
  const float* w    = (const float*)d_in[1];
  const void*  mk   = (const void*)d_in[2];
  const float* bias = (const float*)d_in[3];
  float* out        = (float*)d_out;

  const size_t need = (size_t)MDIM * KDIM * 2 + (size_t)NDIM * KDIM * 2;
  if (ws_size < need) return;

  uint16_t* xh = (uint16_t*)d_ws;
  uint16_t* wh = xh + (size_t)MDIM * KDIM;

  int* flag = (int*)d_out;  // overwritten by GEMM epilogue
  detect_mask_kernel<<<1, 256, 0, stream>>>((const uint32_t*)mk, flag);

  const int nx8 = MDIM * KDIM / 8;  // 4,194,304
  const int nw8 = NDIM * KDIM / 8;  // 2,097,152
  cvt_x_kernel<<<2048, 256, 0, stream>>>(x, xh, nx8);
  cvt_w_kernel<<<2048, 256, 0, stream>>>(w, mk, flag, wh, nw8);

  const int grid = (MDIM / 256) * (NDIM / 256);  // 512
  gemm_bias_256<<<grid, 512, 0, stream>>>(xh, wh, bias, out);
}